// Round 8
// baseline (554.604 us; speedup 1.0000x reference)
//
#include <hip/hip_runtime.h>
#include <hip/hip_bf16.h>

#define NN 50000
#define EE 800000

typedef __attribute__((ext_vector_type(8))) short short8;
typedef __attribute__((ext_vector_type(4))) short short4v;
typedef __attribute__((ext_vector_type(4))) float f32x4;

__device__ __forceinline__ float bf2f(ushort u) {
  union { unsigned u; float f; } v; v.u = ((unsigned)u) << 16; return v.f;
}
__device__ __forceinline__ ushort f2bf(float f) {
  union { float f; unsigned u; } v; v.f = f;
  unsigned r = v.u + 0x7FFFu + ((v.u >> 16) & 1u);  // RNE
  return (ushort)(r >> 16);
}
__device__ __forceinline__ float silu(float v) {
  return v * __builtin_amdgcn_rcpf(1.f + __expf(-v));
}

// ---- prep: weight transposes (bf16) + agg zeroing ----
__global__ void prep_kernel(const float* __restrict__ W1, const float* __restrict__ W2,
                            const float* __restrict__ W3,
                            ushort* __restrict__ W1at, ushort* __restrict__ W1bt,
                            ushort* __restrict__ W2t, ushort* __restrict__ W3t,
                            float* __restrict__ agg) {
  int b = blockIdx.x, tid = threadIdx.x;
  if (b < 200) {                          // weights
    int i = b * 256 + tid;
    if (i < 16384) {                      // W1at [128 n][128 k] = W1[k][n], k<128
      int n = i >> 7, k = i & 127;
      W1at[i] = f2bf(W1[k*128 + n]);
    } else if (i < 32768) {               // W1bt = W1[k+128][n]
      int j = i - 16384, n = j >> 7, k = j & 127;
      W1bt[j] = f2bf(W1[(k + 128)*128 + n]);
    } else if (i < 49152) {               // W2t [128 n][128 k]
      int j = i - 32768, n = j >> 7, k = j & 127;
      W2t[j] = f2bf(W2[k*128 + n]);
    } else if (i < 51200) {               // W3t [16 m][128 k], rows 9..15 zero
      int j = i - 49152, n = j >> 7, k = j & 127;
      W3t[j] = (n < 9) ? f2bf(W3[k*9 + n]) : (ushort)0;
    }
  } else {                                // zero agg
    int i = (b - 200) * 256 + tid;
    if (i < NN*9) agg[i] = 0.f;
  }
}

// ---- node kernel: P = bf16(h@W1a + b1), Q = bf16(h@W1b) ----
__global__ __launch_bounds__(256, 4)
void node_kernel(const float* __restrict__ h,
                 const ushort* __restrict__ W1at, const ushort* __restrict__ W1bt,
                 const float* __restrict__ b1,
                 ushort* __restrict__ P, ushort* __restrict__ Q) {
  __shared__ __align__(16) ushort smH[64*128];      // 16 KB, swizzled
  const int tid = threadIdx.x;
  const int lane = tid & 63;
  const int w   = tid >> 6;
  const int l15 = lane & 15;
  const int lh  = lane >> 4;
  const int wm  = w >> 1;       // 0 -> P (W1at), 1 -> Q (W1bt)
  const int wn  = w & 1;        // node half
  const int n0  = blockIdx.x * 64;

  {   // stage h tile (coalesced), convert to bf16, swizzle
    int e = tid >> 2, p = tid & 3;
    int nn = n0 + e; if (nn >= NN) nn = NN - 1;
    const float* s = h + (size_t)nn*128 + p*32;
    #pragma unroll
    for (int c = 0; c < 4; ++c) {
      float4 a = *(const float4*)(s + c*8);
      float4 bq = *(const float4*)(s + c*8 + 4);
      short8 v;
      v[0]=f2bf(a.x); v[1]=f2bf(a.y); v[2]=f2bf(a.z); v[3]=f2bf(a.w);
      v[4]=f2bf(bq.x); v[5]=f2bf(bq.y); v[6]=f2bf(bq.z); v[7]=f2bf(bq.w);
      int bo = (e*256 + p*64 + c*16) ^ ((e & 7) << 4);
      *(short8*)((char*)smH + bo) = v;
    }
  }
  __syncthreads();

  const ushort* W = wm ? W1bt : W1at;
  f32x4 acc[4][2] = {};
  #pragma unroll
  for (int k0 = 0; k0 < 4; ++k0) {
    short8 a[4], b[2];
    #pragma unroll
    for (int mf = 0; mf < 4; ++mf)
      a[mf] = *(const short8*)(W + (size_t)(mf*16 + l15)*128 + k0*32 + lh*8);
    #pragma unroll
    for (int nf = 0; nf < 2; ++nf) {
      int e = wn*32 + nf*16 + l15;
      int bo = (e*256 + k0*64 + lh*16) ^ ((e & 7) << 4);
      b[nf] = *(const short8*)((char*)smH + bo);
    }
    #pragma unroll
    for (int mf = 0; mf < 4; ++mf)
      #pragma unroll
      for (int nf = 0; nf < 2; ++nf)
        acc[mf][nf] = __builtin_amdgcn_mfma_f32_16x16x32_bf16(a[mf], b[nf], acc[mf][nf], 0, 0, 0);
  }

  #pragma unroll
  for (int mf = 0; mf < 4; ++mf) {
    float4 bq = *(const float4*)(b1 + mf*16 + lh*4);
    #pragma unroll
    for (int nf = 0; nf < 2; ++nf) {
      int node = n0 + wn*32 + nf*16 + l15;
      if (node < NN) {
        f32x4 r = acc[mf][nf];
        if (wm == 0) { r[0]+=bq.x; r[1]+=bq.y; r[2]+=bq.z; r[3]+=bq.w; }
        ushort* dst = (wm ? Q : P) + (size_t)node*128 + mf*16 + lh*4;
        short4v o; o[0]=f2bf(r[0]); o[1]=f2bf(r[1]); o[2]=f2bf(r[2]); o[3]=f2bf(r[3]);
        *(short4v*)dst = o;
      }
    }
  }
}

// ---- edge kernel: ZERO barriers; each wave owns 16 edges end-to-end ----
// Per wave: edges e2 = we..we+15 (l15), full 128-feature dim (mf 0..7 x lh*4+j).
// All LDS slices (smX rows, smPhi, smCd) are wave-private -> lgkmcnt-only ordering.
__global__ __launch_bounds__(256, 4)
void edge_kernel(const ushort* __restrict__ P, const ushort* __restrict__ Q,
                 const float* __restrict__ w1last,
                 const float* __restrict__ g1, const float* __restrict__ be1,
                 const ushort* __restrict__ W2t, const ushort* __restrict__ W3t,
                 const float* __restrict__ b2, const float* __restrict__ g2, const float* __restrict__ be2,
                 const float* __restrict__ edge_attr, const float* __restrict__ edge_mask,
                 const float* __restrict__ coord_diff,
                 const int* __restrict__ row, const int* __restrict__ col,
                 float* __restrict__ agg) {
  // LDS: smX [64][128] bf16 swizzled 16384 | smPhi [64][20] f32 5120 | smCd [64][9] f32 2304
  __shared__ __align__(16) char smem[23808];
  ushort* smX   = (ushort*)smem;
  float*  smPhi = (float*)(smem + 16384);
  float*  smCd  = (float*)(smem + 21504);

  const int tid  = threadIdx.x;
  const int lane = tid & 63;
  const int w    = tid >> 6;
  const int l15  = lane & 15;
  const int lh   = lane >> 4;
  const int e0   = blockIdx.x * 64;
  const int we   = w * 16;                 // wave's first block-local edge

  // ---- phase 1: gather bf16 P[row]+Q[col], pre-LN in regs, LN1 (4-lane shfl), SiLU -> smX
  {
    int e = tid >> 2, p = tid & 3;         // e in [we, we+16) automatically
    int ge = e0 + e;
    int re = row[ge], ce = col[ge];
    float ea = edge_attr[ge];
    const ushort* Pp = P + (size_t)re*128 + p*32;
    const ushort* Qp = Q + (size_t)ce*128 + p*32;
    short8 pa[4], qa[4];
    #pragma unroll
    for (int c = 0; c < 4; ++c) pa[c] = *(const short8*)(Pp + c*8);
    #pragma unroll
    for (int c = 0; c < 4; ++c) qa[c] = *(const short8*)(Qp + c*8);

    // wave-local cd staging (16 edges x 9 floats = 144 = 36 lanes x float4)
    if (lane < 36)
      *(float4*)(smCd + we*9 + lane*4) =
          *(const float4*)(coord_diff + (size_t)(e0 + we)*9 + lane*4);

    float v[32]; float s = 0.f, q = 0.f;
    #pragma unroll
    for (int c = 0; c < 4; ++c) {
      float4 wq0 = *(const float4*)(w1last + p*32 + c*8);
      float4 wq1 = *(const float4*)(w1last + p*32 + c*8 + 4);
      #pragma unroll
      for (int j = 0; j < 8; ++j) {
        float wv = (j < 4) ? ((const float*)&wq0)[j] : ((const float*)&wq1)[j-4];
        float t = bf2f((ushort)pa[c][j]) + bf2f((ushort)qa[c][j]) + ea * wv;
        v[c*8 + j] = t; s += t; q += t*t;
      }
    }
    s += __shfl_xor(s, 1, 64); s += __shfl_xor(s, 2, 64);
    q += __shfl_xor(q, 1, 64); q += __shfl_xor(q, 2, 64);
    float m  = s * (1.f/128.f);
    float rs = rsqrtf(q * (1.f/128.f) - m*m + 1e-5f);
    #pragma unroll
    for (int c = 0; c < 4; ++c) {
      float4 gq0 = *(const float4*)(g1 + p*32 + c*8);
      float4 gq1 = *(const float4*)(g1 + p*32 + c*8 + 4);
      float4 bq0 = *(const float4*)(be1 + p*32 + c*8);
      float4 bq1 = *(const float4*)(be1 + p*32 + c*8 + 4);
      short8 o;
      #pragma unroll
      for (int j = 0; j < 8; ++j) {
        float gv = (j < 4) ? ((const float*)&gq0)[j] : ((const float*)&gq1)[j-4];
        float bv = (j < 4) ? ((const float*)&bq0)[j] : ((const float*)&bq1)[j-4];
        float val = (v[c*8+j] - m) * rs * gv + bv;
        o[j] = f2bf(silu(val));
      }
      int bo = (e*256 + p*64 + c*16) ^ ((e & 7) << 4);
      *(short8*)((char*)smX + bo) = o;
    }
  }
  asm volatile("s_waitcnt lgkmcnt(0)" ::: "memory");   // wave-local x1 visible
  __builtin_amdgcn_sched_barrier(0);

  const int e2 = we + l15;                  // this lane's edge for GEMM phases

  // ---- GEMM2: out2T[n][e2] = sum_k W2t[n][k] * x1[e2][k]  (K=128, wave-local)
  f32x4 acc2[8] = {};
  #pragma unroll
  for (int k0 = 0; k0 < 4; ++k0) {
    int bo = (e2*256 + k0*64 + lh*16) ^ ((e2 & 7) << 4);
    short8 bfrag = *(const short8*)((char*)smX + bo);
    #pragma unroll
    for (int mf = 0; mf < 8; ++mf) {
      short8 a = *(const short8*)(W2t + (size_t)(mf*16 + l15)*128 + k0*32 + lh*8);
      acc2[mf] = __builtin_amdgcn_mfma_f32_16x16x32_bf16(a, bfrag, acc2[mf], 0, 0, 0);
    }
  }

  // ---- epi2 + LN2 (fully in-wave: xor 16, 32) ----
  float s2 = 0.f, q2 = 0.f;
  #pragma unroll
  for (int mf = 0; mf < 8; ++mf) {
    float4 bq = *(const float4*)(b2 + mf*16 + lh*4);
    #pragma unroll
    for (int j = 0; j < 4; ++j) {
      float t = acc2[mf][j] + ((const float*)&bq)[j];
      acc2[mf][j] = t; s2 += t; q2 += t*t;
    }
  }
  s2 += __shfl_xor(s2, 16, 64); s2 += __shfl_xor(s2, 32, 64);
  q2 += __shfl_xor(q2, 16, 64); q2 += __shfl_xor(q2, 32, 64);
  {
    float m  = s2 * (1.f/128.f);
    float rs = rsqrtf(q2 * (1.f/128.f) - m*m + 1e-5f);
    #pragma unroll
    for (int mf = 0; mf < 8; ++mf) {
      float4 gq  = *(const float4*)(g2 + mf*16 + lh*4);
      float4 beq = *(const float4*)(be2 + mf*16 + lh*4);
      short4v o;
      #pragma unroll
      for (int j = 0; j < 4; ++j) {
        float val = (acc2[mf][j] - m) * rs * ((const float*)&gq)[j] + ((const float*)&beq)[j];
        o[j] = f2bf(silu(val));
      }
      int bo = (e2*256 + (mf*16 + lh*4)*2) ^ ((e2 & 7) << 4);
      *(short4v*)((char*)smX + bo) = o;
    }
  }
  asm volatile("s_waitcnt lgkmcnt(0)" ::: "memory");   // wave-local x2 visible
  __builtin_amdgcn_sched_barrier(0);

  // ---- GEMM3: phiT[m3][e2] (M=16 padded, K=128, wave-local) ----
  {
    f32x4 acc3 = {};
    const ushort* A3 = W3t + (size_t)l15 * 128 + lh*8;
    #pragma unroll
    for (int k0 = 0; k0 < 4; ++k0) {
      short8 a = *(const short8*)(A3 + k0*32);
      int bo = (e2*256 + k0*64 + lh*16) ^ ((e2 & 7) << 4);
      short8 b = *(const short8*)((char*)smX + bo);
      acc3 = __builtin_amdgcn_mfma_f32_16x16x32_bf16(a, b, acc3, 0, 0, 0);
    }
    *(float4*)(smPhi + e2*20 + lh*4) = *(float4*)&acc3;
  }
  asm volatile("s_waitcnt lgkmcnt(0)" ::: "memory");   // phi visible to own wave
  __builtin_amdgcn_sched_barrier(0);

  // ---- trans + scatter-add (lanes lh<3; lane's edge = e2) ----
  if (lh < 3) {
    int ge = e0 + e2;
    int re = row[ge];
    float em = edge_mask[ge];
    const float* cd = smCd + e2*9;
    const float* ph = smPhi + e2*20;
    int l = lh;
    #pragma unroll
    for (int k = 0; k < 3; ++k) {
      float t = cd[k]*ph[l] + cd[3+k]*ph[3+l] + cd[6+k]*ph[6+l];
      unsafeAtomicAdd(&agg[(size_t)re*9 + l*3 + k], t * em);
    }
  }
}

__global__ void finalize_kernel(const float* __restrict__ coord, const float* __restrict__ node_mask,
                                const float* __restrict__ agg, float* __restrict__ out) {
  int i = blockIdx.x * 256 + threadIdx.x;
  if (i < NN*9) {
    int n = i / 9;
    out[i] = (coord[i] + agg[i] * 0.01f) * node_mask[n];
  }
}

extern "C" void kernel_launch(void* const* d_in, const int* in_sizes, int n_in,
                              void* d_out, int out_size, void* d_ws, size_t ws_size,
                              hipStream_t stream) {
  const float* h          = (const float*)d_in[0];
  const float* coord      = (const float*)d_in[1];
  const float* coord_diff = (const float*)d_in[2];
  const float* edge_attr  = (const float*)d_in[3];
  const float* edge_mask  = (const float*)d_in[4];
  const float* node_mask  = (const float*)d_in[5];
  const int*   rowi       = (const int*)d_in[6];
  const int*   coli       = (const int*)d_in[7];
  const float* W1  = (const float*)d_in[8];
  const float* b1  = (const float*)d_in[9];
  const float* g1  = (const float*)d_in[10];
  const float* be1 = (const float*)d_in[11];
  const float* W2  = (const float*)d_in[12];
  const float* b2  = (const float*)d_in[13];
  const float* g2  = (const float*)d_in[14];
  const float* be2 = (const float*)d_in[15];
  const float* W3  = (const float*)d_in[16];
  const float* w1last = W1 + 256*128;

  char* ws = (char*)d_ws;
  ushort* P    = (ushort*)ws;                      // 12,800,000
  ushort* Q    = (ushort*)(ws + 12800000);         // 12,800,000
  float*  agg  = (float*)(ws + 25600000);          // 1,800,000 (+pad)
  ushort* W1at = (ushort*)(ws + 27400192);         // 32,768
  ushort* W1bt = (ushort*)(ws + 27432960);         // 32,768
  ushort* W2t  = (ushort*)(ws + 27465728);         // 32,768
  ushort* W3t  = (ushort*)(ws + 27498496);         // 4,096

  const int nodeBlocks = (NN + 63) / 64;           // 782
  const int aggBlocks  = (NN*9 + 255) / 256;       // 1758

  prep_kernel<<<200 + aggBlocks, 256, 0, stream>>>(W1, W2, W3, W1at, W1bt, W2t, W3t, agg);
  node_kernel<<<nodeBlocks, 256, 0, stream>>>(h, W1at, W1bt, b1, P, Q);
  edge_kernel<<<EE/64, 256, 0, stream>>>(P, Q, w1last, g1, be1, W2t, W3t,
      b2, g2, be2, edge_attr, edge_mask, coord_diff, rowi, coli, agg);
  finalize_kernel<<<aggBlocks, 256, 0, stream>>>(coord, node_mask, agg, (float*)d_out);
}